// Round 13
// baseline (703.148 us; speedup 1.0000x reference)
//
#include <hip/hip_runtime.h>

#define NN 100000
#define NE 1600000
#define NB 391        // ceil(NN/256)
#define NS 13         // src slices: slice = src >> 13
#define NSP1 14
#define SLICE_SHIFT 13

__device__ __forceinline__ float rdlane(float v, int i) {
    return __uint_as_float(__builtin_amdgcn_readlane(__float_as_uint(v), (unsigned)i));
}

// ============== build: per-(dst,slice) bucketed CSR (unchanged from R11) ==============

__global__ __launch_bounds__(256) void hist2_k(const int* __restrict__ ei,
                                               int* __restrict__ deg2) {
    int e = blockIdx.x * 256 + threadIdx.x;
    int src = ei[e];
    int dst = ei[NE + e];
    atomicAdd(&deg2[dst * NS + (src >> SLICE_SHIFT)], 1);
}

__global__ __launch_bounds__(256) void rowsum_k(const int* __restrict__ deg2,
                                                int* __restrict__ deg) {
    int i = blockIdx.x * 256 + threadIdx.x;
    if (i < NN) {
        int s = 0;
#pragma unroll
        for (int k = 0; k < NS; ++k) s += deg2[i * NS + k];
        deg[i] = s;
    }
}

__global__ __launch_bounds__(256) void scan1_k(const int* __restrict__ deg,
                                               int* __restrict__ scanned,
                                               int* __restrict__ bsums) {
    __shared__ int tmp[256];
    int i = blockIdx.x * 256 + threadIdx.x;
    int v = (i < NN) ? deg[i] : 0;
    tmp[threadIdx.x] = v;
    __syncthreads();
#pragma unroll
    for (int off = 1; off < 256; off <<= 1) {
        int t = (threadIdx.x >= off) ? tmp[threadIdx.x - off] : 0;
        __syncthreads();
        tmp[threadIdx.x] += t;
        __syncthreads();
    }
    if (i < NN) scanned[i] = tmp[threadIdx.x];
    if (threadIdx.x == 255) bsums[blockIdx.x] = tmp[255];
}

__global__ __launch_bounds__(512) void scan2_k(int* __restrict__ bsums) {
    __shared__ int tmp[512];
    int v = (threadIdx.x < NB) ? bsums[threadIdx.x] : 0;
    tmp[threadIdx.x] = v;
    __syncthreads();
#pragma unroll
    for (int off = 1; off < 512; off <<= 1) {
        int t = (threadIdx.x >= off) ? tmp[threadIdx.x - off] : 0;
        __syncthreads();
        tmp[threadIdx.x] += t;
        __syncthreads();
    }
    if (threadIdx.x < NB) bsums[threadIdx.x] = tmp[threadIdx.x];
}

__global__ __launch_bounds__(256) void scan3b_k(const int* __restrict__ scanned,
                                                const int* __restrict__ bsums,
                                                const int* __restrict__ deg,
                                                const int* __restrict__ deg2,
                                                int* __restrict__ P) {
    int i = blockIdx.x * 256 + threadIdx.x;
    if (i < NN) {
        int incl = scanned[i] + (blockIdx.x ? bsums[blockIdx.x - 1] : 0);
        int run = incl - deg[i];
        P[i * NSP1 + 0] = run;
#pragma unroll
        for (int s = 0; s < NS; ++s) {
            P[i * NSP1 + s + 1] = run;
            run += deg2[i * NS + s];
        }
    }
}

__global__ __launch_bounds__(256) void fill2_k(const int* __restrict__ ei,
                                               int* __restrict__ P,
                                               int* __restrict__ col) {
    int e = blockIdx.x * 256 + threadIdx.x;
    int src = ei[e];
    int dst = ei[NE + e];
    int pos = atomicAdd(&P[dst * NSP1 + (src >> SLICE_SHIFT) + 1], 1);
    col[pos] = src;
}

// ============ layer 1: reg-ILP gather(x) + rdlane-MLP1 -> h ============
__global__ __launch_bounds__(256, 6) void fused1(const float* __restrict__ x,
                                                 const int* __restrict__ P,
                                                 const int* __restrict__ col,
                                                 const float* __restrict__ W1,
                                                 const float* __restrict__ b1,
                                                 const float* __restrict__ W2,
                                                 const float* __restrict__ b2,
                                                 float* __restrict__ h) {
    __shared__ float W1s[32 * 64];
    __shared__ float W2s[64 * 64];
    __shared__ float b1s[64];
    __shared__ float b2s[64];
    for (int i = threadIdx.x; i < 32 * 64; i += 256) W1s[i] = W1[i];
    for (int i = threadIdx.x; i < 64 * 64; i += 256) W2s[i] = W2[i];
    if (threadIdx.x < 64) {
        b1s[threadIdx.x] = b1[threadIdx.x];
        b2s[threadIdx.x] = b2[threadIdx.x];
    }
    __syncthreads();

    int lane = threadIdx.x & 63;
    int c = lane & 31;
    int p = lane >> 5;
    int gw = blockIdx.x * 4 + (threadIdx.x >> 6);
    int nwaves = gridDim.x * 4;

    for (int node = gw; node < NN; node += nwaves) {
        int s0 = P[node * NSP1];
        int s1 = P[node * NSP1 + NS];
        float self = x[(size_t)node * 32 + c];

        float a0 = 0.f, a1 = 0.f, a2 = 0.f, a3 = 0.f;
        int e = s0 + p;
        for (; e + 6 < s1; e += 8) {
            int c0 = col[e], c1 = col[e + 2], c2 = col[e + 4], c3 = col[e + 6];
            a0 += x[(size_t)c0 * 32 + c];
            a1 += x[(size_t)c1 * 32 + c];
            a2 += x[(size_t)c2 * 32 + c];
            a3 += x[(size_t)c3 * 32 + c];
        }
        for (; e < s1; e += 2)
            a0 += x[(size_t)col[e] * 32 + c];
        float acc = (a0 + a1) + (a2 + a3);
        acc += __shfl_xor(acc, 32);
        float aval = acc + self;

        float sa = b1s[lane], sb = 0.f;
#pragma unroll
        for (int i = 0; i < 32; i += 2) {
            sa = fmaf(rdlane(aval, i),     W1s[i * 64 + lane],       sa);
            sb = fmaf(rdlane(aval, i + 1), W1s[(i + 1) * 64 + lane], sb);
        }
        float t = fmaxf(sa + sb, 0.f);

        float s2a = b2s[lane], s2b = 0.f;
#pragma unroll
        for (int j = 0; j < 64; j += 2) {
            s2a = fmaf(rdlane(t, j),     W2s[j * 64 + lane],       s2a);
            s2b = fmaf(rdlane(t, j + 1), W2s[(j + 1) * 64 + lane], s2b);
        }
        h[(size_t)node * 64 + lane] = fmaxf(s2a + s2b, 0.f);
    }
}

// ============ layer 2: reg-ILP gather(h) + rdlane-MLP2 -> out ============
__global__ __launch_bounds__(256, 6) void fused2(const float* __restrict__ h,
                                                 const int* __restrict__ P,
                                                 const int* __restrict__ col,
                                                 const float* __restrict__ W3,
                                                 const float* __restrict__ b3,
                                                 const float* __restrict__ W4,
                                                 const float* __restrict__ b4,
                                                 float* __restrict__ out) {
    __shared__ float W3s[64 * 64];
    __shared__ float W4s[64 * 32];
    __shared__ float b3s[64];
    __shared__ float b4s[32];
    for (int i = threadIdx.x; i < 64 * 64; i += 256) W3s[i] = W3[i];
    for (int i = threadIdx.x; i < 64 * 32; i += 256) W4s[i] = W4[i];
    if (threadIdx.x < 64) b3s[threadIdx.x] = b3[threadIdx.x];
    if (threadIdx.x < 32) b4s[threadIdx.x] = b4[threadIdx.x];
    __syncthreads();

    int lane = threadIdx.x & 63;
    int gw = blockIdx.x * 4 + (threadIdx.x >> 6);
    int nwaves = gridDim.x * 4;

    for (int node = gw; node < NN; node += nwaves) {
        int s0 = P[node * NSP1];
        int s1 = P[node * NSP1 + NS];
        float self = h[(size_t)node * 64 + lane];

        float a0 = 0.f, a1 = 0.f, a2 = 0.f, a3 = 0.f;
        float a4 = 0.f, a5 = 0.f, a6 = 0.f, a7 = 0.f;
        int e = s0;
        for (; e + 7 < s1; e += 8) {
            int c0 = col[e],     c1 = col[e + 1], c2 = col[e + 2], c3 = col[e + 3];
            int c4 = col[e + 4], c5 = col[e + 5], c6 = col[e + 6], c7 = col[e + 7];
            a0 += h[(size_t)c0 * 64 + lane];
            a1 += h[(size_t)c1 * 64 + lane];
            a2 += h[(size_t)c2 * 64 + lane];
            a3 += h[(size_t)c3 * 64 + lane];
            a4 += h[(size_t)c4 * 64 + lane];
            a5 += h[(size_t)c5 * 64 + lane];
            a6 += h[(size_t)c6 * 64 + lane];
            a7 += h[(size_t)c7 * 64 + lane];
        }
        for (; e < s1; ++e)
            a0 += h[(size_t)col[e] * 64 + lane];
        float aval = (((a0 + a1) + (a2 + a3)) + ((a4 + a5) + (a6 + a7))) + self;

        float sa = b3s[lane], sb = 0.f;
#pragma unroll
        for (int i = 0; i < 64; i += 2) {
            sa = fmaf(rdlane(aval, i),     W3s[i * 64 + lane],       sa);
            sb = fmaf(rdlane(aval, i + 1), W3s[(i + 1) * 64 + lane], sb);
        }
        float t = fmaxf(sa + sb, 0.f);

        float s2a = b4s[lane & 31], s2b = 0.f;
#pragma unroll
        for (int j = 0; j < 64; j += 2) {
            s2a = fmaf(rdlane(t, j),     W4s[j * 32 + (lane & 31)],       s2a);
            s2b = fmaf(rdlane(t, j + 1), W4s[(j + 1) * 32 + (lane & 31)], s2b);
        }
        if (lane < 32) out[(size_t)node * 32 + lane] = s2a + s2b;
    }
}

extern "C" void kernel_launch(void* const* d_in, const int* in_sizes, int n_in,
                              void* d_out, int out_size, void* d_ws, size_t ws_size,
                              hipStream_t stream) {
    const float* x  = (const float*)d_in[0];
    const int*   ei = (const int*)d_in[1];
    const float* W1 = (const float*)d_in[2];
    const float* b1 = (const float*)d_in[3];
    const float* W2 = (const float*)d_in[4];
    const float* b2 = (const float*)d_in[5];
    const float* W3 = (const float*)d_in[6];
    const float* b3 = (const float*)d_in[7];
    const float* W4 = (const float*)d_in[8];
    const float* b4 = (const float*)d_in[9];
    float* out = (float*)d_out;

    char* ws = (char*)d_ws;
    float* h   = (float*)ws;                          ws += (size_t)NN * 64 * 4;       // 25.6 MB
    int*   col = (int*)ws;                            ws += (size_t)NE * 4;            // 6.4 MB
    int*   P   = (int*)ws;                            ws += (size_t)NN * NSP1 * 4;     // 5.6 MB

    // build-time arrays overlay the h region (dead before fused1 writes h)
    char* ov = (char*)h;
    int* deg2    = (int*)ov;                          ov += (size_t)NN * NS * 4;       // 5.2 MB
    int* deg     = (int*)ov;                          ov += (size_t)NN * 4;
    int* scanned = (int*)ov;                          ov += (size_t)NN * 4;
    int* bsums   = (int*)ov;                          ov += (size_t)NB * 4;

    // ---- slice-bucketed CSR build ----
    hipMemsetAsync(deg2, 0, (size_t)NN * NS * 4, stream);
    hist2_k<<<NE / 256, 256, 0, stream>>>(ei, deg2);
    rowsum_k<<<NB, 256, 0, stream>>>(deg2, deg);
    scan1_k<<<NB, 256, 0, stream>>>(deg, scanned, bsums);
    scan2_k<<<1, 512, 0, stream>>>(bsums);
    scan3b_k<<<NB, 256, 0, stream>>>(scanned, bsums, deg, deg2, P);
    fill2_k<<<NE / 256, 256, 0, stream>>>(ei, P, col);

    // ---- fused layers ----
    fused1<<<1536, 256, 0, stream>>>(x, P, col, W1, b1, W2, b2, h);
    fused2<<<1536, 256, 0, stream>>>(h, P, col, W3, b3, W4, b4, out);
}

// Round 14
// 477.157 us; speedup vs baseline: 1.4736x; 1.4736x over previous
//
#include <hip/hip_runtime.h>

#define NN 100000
#define NE 1600000
#define NB 391        // ceil(NN/256)
#define NS 13         // src slices: slice = src >> 13
#define NSP1 14
#define SLICE_SHIFT 13

__device__ __forceinline__ float rdlane(float v, int i) {
    return __uint_as_float(__builtin_amdgcn_readlane(__float_as_uint(v), (unsigned)i));
}

// ============== build: per-(dst,slice) bucketed CSR (unchanged from R11) ==============

__global__ __launch_bounds__(256) void hist2_k(const int* __restrict__ ei,
                                               int* __restrict__ deg2) {
    int e = blockIdx.x * 256 + threadIdx.x;
    int src = ei[e];
    int dst = ei[NE + e];
    atomicAdd(&deg2[dst * NS + (src >> SLICE_SHIFT)], 1);
}

__global__ __launch_bounds__(256) void rowsum_k(const int* __restrict__ deg2,
                                                int* __restrict__ deg) {
    int i = blockIdx.x * 256 + threadIdx.x;
    if (i < NN) {
        int s = 0;
#pragma unroll
        for (int k = 0; k < NS; ++k) s += deg2[i * NS + k];
        deg[i] = s;
    }
}

__global__ __launch_bounds__(256) void scan1_k(const int* __restrict__ deg,
                                               int* __restrict__ scanned,
                                               int* __restrict__ bsums) {
    __shared__ int tmp[256];
    int i = blockIdx.x * 256 + threadIdx.x;
    int v = (i < NN) ? deg[i] : 0;
    tmp[threadIdx.x] = v;
    __syncthreads();
#pragma unroll
    for (int off = 1; off < 256; off <<= 1) {
        int t = (threadIdx.x >= off) ? tmp[threadIdx.x - off] : 0;
        __syncthreads();
        tmp[threadIdx.x] += t;
        __syncthreads();
    }
    if (i < NN) scanned[i] = tmp[threadIdx.x];
    if (threadIdx.x == 255) bsums[blockIdx.x] = tmp[255];
}

__global__ __launch_bounds__(512) void scan2_k(int* __restrict__ bsums) {
    __shared__ int tmp[512];
    int v = (threadIdx.x < NB) ? bsums[threadIdx.x] : 0;
    tmp[threadIdx.x] = v;
    __syncthreads();
#pragma unroll
    for (int off = 1; off < 512; off <<= 1) {
        int t = (threadIdx.x >= off) ? tmp[threadIdx.x - off] : 0;
        __syncthreads();
        tmp[threadIdx.x] += t;
        __syncthreads();
    }
    if (threadIdx.x < NB) bsums[threadIdx.x] = tmp[threadIdx.x];
}

__global__ __launch_bounds__(256) void scan3b_k(const int* __restrict__ scanned,
                                                const int* __restrict__ bsums,
                                                const int* __restrict__ deg,
                                                const int* __restrict__ deg2,
                                                int* __restrict__ P) {
    int i = blockIdx.x * 256 + threadIdx.x;
    if (i < NN) {
        int incl = scanned[i] + (blockIdx.x ? bsums[blockIdx.x - 1] : 0);
        int run = incl - deg[i];
        P[i * NSP1 + 0] = run;
#pragma unroll
        for (int s = 0; s < NS; ++s) {
            P[i * NSP1 + s + 1] = run;
            run += deg2[i * NS + s];
        }
    }
}

__global__ __launch_bounds__(256) void fill2_k(const int* __restrict__ ei,
                                               int* __restrict__ P,
                                               int* __restrict__ col) {
    int e = blockIdx.x * 256 + threadIdx.x;
    int src = ei[e];
    int dst = ei[NE + e];
    int pos = atomicAdd(&P[dst * NSP1 + (src >> SLICE_SHIFT) + 1], 1);
    col[pos] = src;
}

// ============ layer 1: reg-ILP gather(x) + rdlane-MLP1 -> h ============
__global__ __launch_bounds__(256) void fused1(const float* __restrict__ x,
                                              const int* __restrict__ P,
                                              const int* __restrict__ col,
                                              const float* __restrict__ W1,
                                              const float* __restrict__ b1,
                                              const float* __restrict__ W2,
                                              const float* __restrict__ b2,
                                              float* __restrict__ h) {
    __shared__ float W1s[32 * 64];
    __shared__ float W2s[64 * 64];
    __shared__ float b1s[64];
    __shared__ float b2s[64];
    for (int i = threadIdx.x; i < 32 * 64; i += 256) W1s[i] = W1[i];
    for (int i = threadIdx.x; i < 64 * 64; i += 256) W2s[i] = W2[i];
    if (threadIdx.x < 64) {
        b1s[threadIdx.x] = b1[threadIdx.x];
        b2s[threadIdx.x] = b2[threadIdx.x];
    }
    __syncthreads();

    int lane = threadIdx.x & 63;
    int c = lane & 31;
    int p = lane >> 5;
    int gw = blockIdx.x * 4 + (threadIdx.x >> 6);
    int nwaves = gridDim.x * 4;

    for (int node = gw; node < NN; node += nwaves) {
        int s0 = P[node * NSP1];
        int s1 = P[node * NSP1 + NS];
        float self = x[(size_t)node * 32 + c];

        float a0 = 0.f, a1 = 0.f, a2 = 0.f, a3 = 0.f;
        int e = s0 + p;
        for (; e + 6 < s1; e += 8) {
            int c0 = col[e], c1 = col[e + 2], c2 = col[e + 4], c3 = col[e + 6];
            a0 += x[(size_t)c0 * 32 + c];
            a1 += x[(size_t)c1 * 32 + c];
            a2 += x[(size_t)c2 * 32 + c];
            a3 += x[(size_t)c3 * 32 + c];
        }
        for (; e < s1; e += 2)
            a0 += x[(size_t)col[e] * 32 + c];
        float acc = (a0 + a1) + (a2 + a3);
        acc += __shfl_xor(acc, 32);
        float aval = acc + self;

        float sa = b1s[lane], sb = 0.f;
#pragma unroll
        for (int i = 0; i < 32; i += 2) {
            sa = fmaf(rdlane(aval, i),     W1s[i * 64 + lane],       sa);
            sb = fmaf(rdlane(aval, i + 1), W1s[(i + 1) * 64 + lane], sb);
        }
        float t = fmaxf(sa + sb, 0.f);

        float s2a = b2s[lane], s2b = 0.f;
#pragma unroll
        for (int j = 0; j < 64; j += 2) {
            s2a = fmaf(rdlane(t, j),     W2s[j * 64 + lane],       s2a);
            s2b = fmaf(rdlane(t, j + 1), W2s[(j + 1) * 64 + lane], s2b);
        }
        h[(size_t)node * 64 + lane] = fmaxf(s2a + s2b, 0.f);
    }
}

// ============ layer 2: reg-ILP gather(h) + rdlane-MLP2 -> out ============
__global__ __launch_bounds__(256) void fused2(const float* __restrict__ h,
                                              const int* __restrict__ P,
                                              const int* __restrict__ col,
                                              const float* __restrict__ W3,
                                              const float* __restrict__ b3,
                                              const float* __restrict__ W4,
                                              const float* __restrict__ b4,
                                              float* __restrict__ out) {
    __shared__ float W3s[64 * 64];
    __shared__ float W4s[64 * 32];
    __shared__ float b3s[64];
    __shared__ float b4s[32];
    for (int i = threadIdx.x; i < 64 * 64; i += 256) W3s[i] = W3[i];
    for (int i = threadIdx.x; i < 64 * 32; i += 256) W4s[i] = W4[i];
    if (threadIdx.x < 64) b3s[threadIdx.x] = b3[threadIdx.x];
    if (threadIdx.x < 32) b4s[threadIdx.x] = b4[threadIdx.x];
    __syncthreads();

    int lane = threadIdx.x & 63;
    int gw = blockIdx.x * 4 + (threadIdx.x >> 6);
    int nwaves = gridDim.x * 4;

    for (int node = gw; node < NN; node += nwaves) {
        int s0 = P[node * NSP1];
        int s1 = P[node * NSP1 + NS];
        float self = h[(size_t)node * 64 + lane];

        float a0 = 0.f, a1 = 0.f, a2 = 0.f, a3 = 0.f;
        float a4 = 0.f, a5 = 0.f, a6 = 0.f, a7 = 0.f;
        int e = s0;
        for (; e + 7 < s1; e += 8) {
            int c0 = col[e],     c1 = col[e + 1], c2 = col[e + 2], c3 = col[e + 3];
            int c4 = col[e + 4], c5 = col[e + 5], c6 = col[e + 6], c7 = col[e + 7];
            a0 += h[(size_t)c0 * 64 + lane];
            a1 += h[(size_t)c1 * 64 + lane];
            a2 += h[(size_t)c2 * 64 + lane];
            a3 += h[(size_t)c3 * 64 + lane];
            a4 += h[(size_t)c4 * 64 + lane];
            a5 += h[(size_t)c5 * 64 + lane];
            a6 += h[(size_t)c6 * 64 + lane];
            a7 += h[(size_t)c7 * 64 + lane];
        }
        for (; e < s1; ++e)
            a0 += h[(size_t)col[e] * 64 + lane];
        float aval = (((a0 + a1) + (a2 + a3)) + ((a4 + a5) + (a6 + a7))) + self;

        float sa = b3s[lane], sb = 0.f;
#pragma unroll
        for (int i = 0; i < 64; i += 2) {
            sa = fmaf(rdlane(aval, i),     W3s[i * 64 + lane],       sa);
            sb = fmaf(rdlane(aval, i + 1), W3s[(i + 1) * 64 + lane], sb);
        }
        float t = fmaxf(sa + sb, 0.f);

        float s2a = b4s[lane & 31], s2b = 0.f;
#pragma unroll
        for (int j = 0; j < 64; j += 2) {
            s2a = fmaf(rdlane(t, j),     W4s[j * 32 + (lane & 31)],       s2a);
            s2b = fmaf(rdlane(t, j + 1), W4s[(j + 1) * 32 + (lane & 31)], s2b);
        }
        if (lane < 32) out[(size_t)node * 32 + lane] = s2a + s2b;
    }
}

extern "C" void kernel_launch(void* const* d_in, const int* in_sizes, int n_in,
                              void* d_out, int out_size, void* d_ws, size_t ws_size,
                              hipStream_t stream) {
    const float* x  = (const float*)d_in[0];
    const int*   ei = (const int*)d_in[1];
    const float* W1 = (const float*)d_in[2];
    const float* b1 = (const float*)d_in[3];
    const float* W2 = (const float*)d_in[4];
    const float* b2 = (const float*)d_in[5];
    const float* W3 = (const float*)d_in[6];
    const float* b3 = (const float*)d_in[7];
    const float* W4 = (const float*)d_in[8];
    const float* b4 = (const float*)d_in[9];
    float* out = (float*)d_out;

    char* ws = (char*)d_ws;
    float* h   = (float*)ws;                          ws += (size_t)NN * 64 * 4;       // 25.6 MB
    int*   col = (int*)ws;                            ws += (size_t)NE * 4;            // 6.4 MB
    int*   P   = (int*)ws;                            ws += (size_t)NN * NSP1 * 4;     // 5.6 MB

    // build-time arrays overlay the h region (dead before fused1 writes h)
    char* ov = (char*)h;
    int* deg2    = (int*)ov;                          ov += (size_t)NN * NS * 4;       // 5.2 MB
    int* deg     = (int*)ov;                          ov += (size_t)NN * 4;
    int* scanned = (int*)ov;                          ov += (size_t)NN * 4;
    int* bsums   = (int*)ov;                          ov += (size_t)NB * 4;

    // ---- slice-bucketed CSR build ----
    hipMemsetAsync(deg2, 0, (size_t)NN * NS * 4, stream);
    hist2_k<<<NE / 256, 256, 0, stream>>>(ei, deg2);
    rowsum_k<<<NB, 256, 0, stream>>>(deg2, deg);
    scan1_k<<<NB, 256, 0, stream>>>(deg, scanned, bsums);
    scan2_k<<<1, 512, 0, stream>>>(bsums);
    scan3b_k<<<NB, 256, 0, stream>>>(scanned, bsums, deg, deg2, P);
    fill2_k<<<NE / 256, 256, 0, stream>>>(ei, P, col);

    // ---- fused layers ----
    fused1<<<1536, 256, 0, stream>>>(x, P, col, W1, b1, W2, b2, h);
    fused2<<<1536, 256, 0, stream>>>(h, P, col, W3, b3, W4, b4, out);
}

// Round 15
// 463.389 us; speedup vs baseline: 1.5174x; 1.0297x over previous
//
#include <hip/hip_runtime.h>
#include <hip/hip_fp16.h>

#define NN 100000
#define NE 1600000
#define NB 391        // ceil(NN/256)
#define NS 13         // src slices: slice = src >> 13
#define NSP1 14
#define SLICE_SHIFT 13

__device__ __forceinline__ float rdlane(float v, int i) {
    return __uint_as_float(__builtin_amdgcn_readlane(__float_as_uint(v), (unsigned)i));
}

// ============== build: per-(dst,slice) bucketed CSR ==============

__global__ __launch_bounds__(256) void hist2_k(const int* __restrict__ ei,
                                               int* __restrict__ deg2) {
    int e = blockIdx.x * 256 + threadIdx.x;
    int src = ei[e];
    int dst = ei[NE + e];
    atomicAdd(&deg2[dst * NS + (src >> SLICE_SHIFT)], 1);
}

// scan1 with fused row-sum (reads deg2 directly; no separate rowsum pass)
__global__ __launch_bounds__(256) void scan1_k(const int* __restrict__ deg2,
                                               int* __restrict__ scanned,
                                               int* __restrict__ bsums) {
    __shared__ int tmp[256];
    int i = blockIdx.x * 256 + threadIdx.x;
    int v = 0;
    if (i < NN) {
#pragma unroll
        for (int k = 0; k < NS; ++k) v += deg2[i * NS + k];
    }
    tmp[threadIdx.x] = v;
    __syncthreads();
#pragma unroll
    for (int off = 1; off < 256; off <<= 1) {
        int t = (threadIdx.x >= off) ? tmp[threadIdx.x - off] : 0;
        __syncthreads();
        tmp[threadIdx.x] += t;
        __syncthreads();
    }
    if (i < NN) scanned[i] = tmp[threadIdx.x];
    if (threadIdx.x == 255) bsums[blockIdx.x] = tmp[255];
}

__global__ __launch_bounds__(512) void scan2_k(int* __restrict__ bsums) {
    __shared__ int tmp[512];
    int v = (threadIdx.x < NB) ? bsums[threadIdx.x] : 0;
    tmp[threadIdx.x] = v;
    __syncthreads();
#pragma unroll
    for (int off = 1; off < 512; off <<= 1) {
        int t = (threadIdx.x >= off) ? tmp[threadIdx.x - off] : 0;
        __syncthreads();
        tmp[threadIdx.x] += t;
        __syncthreads();
    }
    if (threadIdx.x < NB) bsums[threadIdx.x] = tmp[threadIdx.x];
}

__global__ __launch_bounds__(256) void scan3b_k(const int* __restrict__ scanned,
                                                const int* __restrict__ bsums,
                                                const int* __restrict__ deg2,
                                                int* __restrict__ P) {
    int i = blockIdx.x * 256 + threadIdx.x;
    if (i < NN) {
        int d = 0;
#pragma unroll
        for (int k = 0; k < NS; ++k) d += deg2[i * NS + k];
        int incl = scanned[i] + (blockIdx.x ? bsums[blockIdx.x - 1] : 0);
        int run = incl - d;
        P[i * NSP1 + 0] = run;
#pragma unroll
        for (int s = 0; s < NS; ++s) {
            P[i * NSP1 + s + 1] = run;
            run += deg2[i * NS + s];
        }
    }
}

__global__ __launch_bounds__(256) void fill2_k(const int* __restrict__ ei,
                                               int* __restrict__ P,
                                               int* __restrict__ col) {
    int e = blockIdx.x * 256 + threadIdx.x;
    int src = ei[e];
    int dst = ei[NE + e];
    int pos = atomicAdd(&P[dst * NSP1 + (src >> SLICE_SHIFT) + 1], 1);
    col[pos] = src;
}

// ---- x (f32) -> x16 (half2-packed) ----
__global__ __launch_bounds__(256) void cvt_k(const float2* __restrict__ x2,
                                             __half2* __restrict__ x16) {
    int i = blockIdx.x * 256 + threadIdx.x;
    if (i < NN * 16) {
        float2 v = x2[i];
        x16[i] = __floats2half2_rn(v.x, v.y);
    }
}

// ============ layer 1: fp16 gather(x16) + rdlane-MLP1 -> h16 ============
// lane = (edge group g = lane>>4) x (channel pair cp = lane&15); half2 loads.
__global__ __launch_bounds__(256) void fused1(const float* __restrict__ x,
                                              const __half2* __restrict__ x16,
                                              const int* __restrict__ P,
                                              const int* __restrict__ col,
                                              const float* __restrict__ W1,
                                              const float* __restrict__ b1,
                                              const float* __restrict__ W2,
                                              const float* __restrict__ b2,
                                              __half* __restrict__ h16) {
    __shared__ float W1s[32 * 64];
    __shared__ float W2s[64 * 64];
    __shared__ float b1s[64];
    __shared__ float b2s[64];
    for (int i = threadIdx.x; i < 32 * 64; i += 256) W1s[i] = W1[i];
    for (int i = threadIdx.x; i < 64 * 64; i += 256) W2s[i] = W2[i];
    if (threadIdx.x < 64) {
        b1s[threadIdx.x] = b1[threadIdx.x];
        b2s[threadIdx.x] = b2[threadIdx.x];
    }
    __syncthreads();

    int lane = threadIdx.x & 63;
    int cp = lane & 15;
    int g = lane >> 4;
    int gw = blockIdx.x * 4 + (threadIdx.x >> 6);
    int nwaves = gridDim.x * 4;

    for (int node = gw; node < NN; node += nwaves) {
        int s0 = P[node * NSP1];
        int s1 = P[node * NSP1 + NS];
        float2 sf = ((const float2*)x)[(size_t)node * 16 + cp];  // self, f32

        float ax0 = 0.f, ax1 = 0.f, ax2 = 0.f, ax3 = 0.f;
        float ay0 = 0.f, ay1 = 0.f, ay2 = 0.f, ay3 = 0.f;
        int e = s0 + g;
        for (; e + 12 < s1; e += 16) {
            int c0 = col[e], c1 = col[e + 4], c2 = col[e + 8], c3 = col[e + 12];
            float2 f0 = __half22float2(x16[(size_t)c0 * 16 + cp]);
            float2 f1 = __half22float2(x16[(size_t)c1 * 16 + cp]);
            float2 f2 = __half22float2(x16[(size_t)c2 * 16 + cp]);
            float2 f3 = __half22float2(x16[(size_t)c3 * 16 + cp]);
            ax0 += f0.x; ay0 += f0.y;
            ax1 += f1.x; ay1 += f1.y;
            ax2 += f2.x; ay2 += f2.y;
            ax3 += f3.x; ay3 += f3.y;
        }
        for (; e < s1; e += 4) {
            float2 f = __half22float2(x16[(size_t)col[e] * 16 + cp]);
            ax0 += f.x; ay0 += f.y;
        }
        float avx = (ax0 + ax1) + (ax2 + ax3);
        float avy = (ay0 + ay1) + (ay2 + ay3);
        avx += __shfl_xor(avx, 16); avx += __shfl_xor(avx, 32);
        avy += __shfl_xor(avy, 16); avy += __shfl_xor(avy, 32);
        avx += sf.x; avy += sf.y;

        // MLP1: input ch 2k -> rdlane(avx,k), ch 2k+1 -> rdlane(avy,k)
        float sa = b1s[lane], sb = 0.f;
#pragma unroll
        for (int i = 0; i < 16; ++i) {
            sa = fmaf(rdlane(avx, i), W1s[(2 * i) * 64 + lane],     sa);
            sb = fmaf(rdlane(avy, i), W1s[(2 * i + 1) * 64 + lane], sb);
        }
        float t = fmaxf(sa + sb, 0.f);

        float s2a = b2s[lane], s2b = 0.f;
#pragma unroll
        for (int j = 0; j < 64; j += 2) {
            s2a = fmaf(rdlane(t, j),     W2s[j * 64 + lane],       s2a);
            s2b = fmaf(rdlane(t, j + 1), W2s[(j + 1) * 64 + lane], s2b);
        }
        h16[(size_t)node * 64 + lane] = __float2half(fmaxf(s2a + s2b, 0.f));
    }
}

// ============ layer 2: fp16 gather(h16) + rdlane-MLP2 -> out ============
// lane = (parity p = lane>>5) x (channel pair cp = lane&31); 8-deep unroll.
__global__ __launch_bounds__(256) void fused2(const __half2* __restrict__ h2,
                                              const int* __restrict__ P,
                                              const int* __restrict__ col,
                                              const float* __restrict__ W3,
                                              const float* __restrict__ b3,
                                              const float* __restrict__ W4,
                                              const float* __restrict__ b4,
                                              float* __restrict__ out) {
    __shared__ float W3s[64 * 64];
    __shared__ float W4s[64 * 32];
    __shared__ float b3s[64];
    __shared__ float b4s[32];
    for (int i = threadIdx.x; i < 64 * 64; i += 256) W3s[i] = W3[i];
    for (int i = threadIdx.x; i < 64 * 32; i += 256) W4s[i] = W4[i];
    if (threadIdx.x < 64) b3s[threadIdx.x] = b3[threadIdx.x];
    if (threadIdx.x < 32) b4s[threadIdx.x] = b4[threadIdx.x];
    __syncthreads();

    int lane = threadIdx.x & 63;
    int cp = lane & 31;
    int p = lane >> 5;
    int gw = blockIdx.x * 4 + (threadIdx.x >> 6);
    int nwaves = gridDim.x * 4;

    for (int node = gw; node < NN; node += nwaves) {
        int s0 = P[node * NSP1];
        int s1 = P[node * NSP1 + NS];
        float2 sf = __half22float2(h2[(size_t)node * 32 + cp]);  // self

        float ax0 = 0.f, ax1 = 0.f, ax2 = 0.f, ax3 = 0.f;
        float ax4 = 0.f, ax5 = 0.f, ax6 = 0.f, ax7 = 0.f;
        float ay0 = 0.f, ay1 = 0.f, ay2 = 0.f, ay3 = 0.f;
        float ay4 = 0.f, ay5 = 0.f, ay6 = 0.f, ay7 = 0.f;
        int e = s0 + p;
        for (; e + 14 < s1; e += 16) {           // parity edges e, e+2, ..., e+14
            int c0 = col[e],      c1 = col[e + 2],  c2 = col[e + 4],  c3 = col[e + 6];
            int c4 = col[e + 8],  c5 = col[e + 10], c6 = col[e + 12], c7 = col[e + 14];
            float2 f0 = __half22float2(h2[(size_t)c0 * 32 + cp]);
            float2 f1 = __half22float2(h2[(size_t)c1 * 32 + cp]);
            float2 f2 = __half22float2(h2[(size_t)c2 * 32 + cp]);
            float2 f3 = __half22float2(h2[(size_t)c3 * 32 + cp]);
            float2 f4 = __half22float2(h2[(size_t)c4 * 32 + cp]);
            float2 f5 = __half22float2(h2[(size_t)c5 * 32 + cp]);
            float2 f6 = __half22float2(h2[(size_t)c6 * 32 + cp]);
            float2 f7 = __half22float2(h2[(size_t)c7 * 32 + cp]);
            ax0 += f0.x; ay0 += f0.y;
            ax1 += f1.x; ay1 += f1.y;
            ax2 += f2.x; ay2 += f2.y;
            ax3 += f3.x; ay3 += f3.y;
            ax4 += f4.x; ay4 += f4.y;
            ax5 += f5.x; ay5 += f5.y;
            ax6 += f6.x; ay6 += f6.y;
            ax7 += f7.x; ay7 += f7.y;
        }
        for (; e < s1; e += 2) {
            float2 f = __half22float2(h2[(size_t)col[e] * 32 + cp]);
            ax0 += f.x; ay0 += f.y;
        }
        float avx = ((ax0 + ax1) + (ax2 + ax3)) + ((ax4 + ax5) + (ax6 + ax7));
        float avy = ((ay0 + ay1) + (ay2 + ay3)) + ((ay4 + ay5) + (ay6 + ay7));
        avx += __shfl_xor(avx, 32);
        avy += __shfl_xor(avy, 32);
        avx += sf.x; avy += sf.y;

        // MLP2: input ch 2k -> rdlane(avx,k), ch 2k+1 -> rdlane(avy,k), k=0..31
        float sa = b3s[lane], sb = 0.f;
#pragma unroll
        for (int i = 0; i < 32; ++i) {
            sa = fmaf(rdlane(avx, i), W3s[(2 * i) * 64 + lane],     sa);
            sb = fmaf(rdlane(avy, i), W3s[(2 * i + 1) * 64 + lane], sb);
        }
        float t = fmaxf(sa + sb, 0.f);

        float s2a = b4s[lane & 31], s2b = 0.f;
#pragma unroll
        for (int j = 0; j < 64; j += 2) {
            s2a = fmaf(rdlane(t, j),     W4s[j * 32 + (lane & 31)],       s2a);
            s2b = fmaf(rdlane(t, j + 1), W4s[(j + 1) * 32 + (lane & 31)], s2b);
        }
        if (lane < 32) out[(size_t)node * 32 + lane] = s2a + s2b;
    }
}

extern "C" void kernel_launch(void* const* d_in, const int* in_sizes, int n_in,
                              void* d_out, int out_size, void* d_ws, size_t ws_size,
                              hipStream_t stream) {
    const float* x  = (const float*)d_in[0];
    const int*   ei = (const int*)d_in[1];
    const float* W1 = (const float*)d_in[2];
    const float* b1 = (const float*)d_in[3];
    const float* W2 = (const float*)d_in[4];
    const float* b2 = (const float*)d_in[5];
    const float* W3 = (const float*)d_in[6];
    const float* b3 = (const float*)d_in[7];
    const float* W4 = (const float*)d_in[8];
    const float* b4 = (const float*)d_in[9];
    float* out = (float*)d_out;

    char* ws = (char*)d_ws;
    __half* h16 = (__half*)ws;                        ws += (size_t)NN * 64 * 2;       // 12.8 MB
    __half* x16 = (__half*)ws;                        ws += (size_t)NN * 32 * 2;       // 6.4 MB
    int*   col  = (int*)ws;                           ws += (size_t)NE * 4;            // 6.4 MB
    int*   P    = (int*)ws;                           ws += (size_t)NN * NSP1 * 4;     // 5.6 MB
    int*   deg2 = (int*)ws;                           ws += (size_t)NN * NS * 4;       // 5.2 MB
    int* scanned= (int*)ws;                           ws += (size_t)NN * 4;
    int*   bsums= (int*)ws;                           ws += (size_t)NB * 4;

    // ---- slice-bucketed CSR build + fp16 conversion ----
    hipMemsetAsync(deg2, 0, (size_t)NN * NS * 4, stream);
    cvt_k<<<(NN * 16 + 255) / 256, 256, 0, stream>>>((const float2*)x, (__half2*)x16);
    hist2_k<<<NE / 256, 256, 0, stream>>>(ei, deg2);
    scan1_k<<<NB, 256, 0, stream>>>(deg2, scanned, bsums);
    scan2_k<<<1, 512, 0, stream>>>(bsums);
    scan3b_k<<<NB, 256, 0, stream>>>(scanned, bsums, deg2, P);
    fill2_k<<<NE / 256, 256, 0, stream>>>(ei, P, col);

    // ---- fused layers ----
    fused1<<<1536, 256, 0, stream>>>(x, (const __half2*)x16, P, col,
                                     W1, b1, W2, b2, h16);
    fused2<<<1536, 256, 0, stream>>>((const __half2*)h16, P, col,
                                     W3, b3, W4, b4, out);
}

// Round 16
// 407.711 us; speedup vs baseline: 1.7246x; 1.1366x over previous
//
#include <hip/hip_runtime.h>
#include <hip/hip_fp16.h>

#define NN 100000
#define NE 1600000
#define NB 391        // ceil(NN/256)
#define NS 13         // src slices: slice = src >> 13
#define NSP1 14
#define SLICE_SHIFT 13

__device__ __forceinline__ float rdlane(float v, int i) {
    return __uint_as_float(__builtin_amdgcn_readlane(__float_as_uint(v), (unsigned)i));
}

// unpack 4 halves (carried in a float2) and accumulate into 4 f32 chains
__device__ __forceinline__ void h4acc(float2 raw, float& ax, float& ay, float& az, float& aw) {
    __half2 lo = *reinterpret_cast<__half2*>(&raw.x);
    __half2 hi = *reinterpret_cast<__half2*>(&raw.y);
    float2 a = __half22float2(lo);
    float2 b = __half22float2(hi);
    ax += a.x; ay += a.y; az += b.x; aw += b.y;
}

// ============== build: per-(dst,slice) bucketed CSR (unchanged) ==============

__global__ __launch_bounds__(256) void hist2_k(const int* __restrict__ ei,
                                               int* __restrict__ deg2) {
    int e = blockIdx.x * 256 + threadIdx.x;
    int src = ei[e];
    int dst = ei[NE + e];
    atomicAdd(&deg2[dst * NS + (src >> SLICE_SHIFT)], 1);
}

__global__ __launch_bounds__(256) void scan1_k(const int* __restrict__ deg2,
                                               int* __restrict__ scanned,
                                               int* __restrict__ bsums) {
    __shared__ int tmp[256];
    int i = blockIdx.x * 256 + threadIdx.x;
    int v = 0;
    if (i < NN) {
#pragma unroll
        for (int k = 0; k < NS; ++k) v += deg2[i * NS + k];
    }
    tmp[threadIdx.x] = v;
    __syncthreads();
#pragma unroll
    for (int off = 1; off < 256; off <<= 1) {
        int t = (threadIdx.x >= off) ? tmp[threadIdx.x - off] : 0;
        __syncthreads();
        tmp[threadIdx.x] += t;
        __syncthreads();
    }
    if (i < NN) scanned[i] = tmp[threadIdx.x];
    if (threadIdx.x == 255) bsums[blockIdx.x] = tmp[255];
}

__global__ __launch_bounds__(512) void scan2_k(int* __restrict__ bsums) {
    __shared__ int tmp[512];
    int v = (threadIdx.x < NB) ? bsums[threadIdx.x] : 0;
    tmp[threadIdx.x] = v;
    __syncthreads();
#pragma unroll
    for (int off = 1; off < 512; off <<= 1) {
        int t = (threadIdx.x >= off) ? tmp[threadIdx.x - off] : 0;
        __syncthreads();
        tmp[threadIdx.x] += t;
        __syncthreads();
    }
    if (threadIdx.x < NB) bsums[threadIdx.x] = tmp[threadIdx.x];
}

__global__ __launch_bounds__(256) void scan3b_k(const int* __restrict__ scanned,
                                                const int* __restrict__ bsums,
                                                const int* __restrict__ deg2,
                                                int* __restrict__ P) {
    int i = blockIdx.x * 256 + threadIdx.x;
    if (i < NN) {
        int d = 0;
#pragma unroll
        for (int k = 0; k < NS; ++k) d += deg2[i * NS + k];
        int incl = scanned[i] + (blockIdx.x ? bsums[blockIdx.x - 1] : 0);
        int run = incl - d;
        P[i * NSP1 + 0] = run;
#pragma unroll
        for (int s = 0; s < NS; ++s) {
            P[i * NSP1 + s + 1] = run;
            run += deg2[i * NS + s];
        }
    }
}

__global__ __launch_bounds__(256) void fill2_k(const int* __restrict__ ei,
                                               int* __restrict__ P,
                                               int* __restrict__ col) {
    int e = blockIdx.x * 256 + threadIdx.x;
    int src = ei[e];
    int dst = ei[NE + e];
    int pos = atomicAdd(&P[dst * NSP1 + (src >> SLICE_SHIFT) + 1], 1);
    col[pos] = src;
}

// ---- x (f32) -> x16 (half-packed) ----
__global__ __launch_bounds__(256) void cvt_k(const float2* __restrict__ x2,
                                             __half2* __restrict__ x16) {
    int i = blockIdx.x * 256 + threadIdx.x;
    if (i < NN * 16) {
        float2 v = x2[i];
        x16[i] = __floats2half2_rn(v.x, v.y);
    }
}

// ============ layer 1: half4 gather(x16) + rdlane-MLP1 -> h16 ============
// lane = (edge slot g = lane>>3, 0..7) x (channel quad cq = lane&7 -> ch 4cq..4cq+3)
// 8 edges per VMEM instruction; 2-deep unroll (16 edges in flight per wave).
__global__ __launch_bounds__(256) void fused1(const float* __restrict__ x,
                                              const float2* __restrict__ x16f2,
                                              const int* __restrict__ P,
                                              const int* __restrict__ col,
                                              const float* __restrict__ W1,
                                              const float* __restrict__ b1,
                                              const float* __restrict__ W2,
                                              const float* __restrict__ b2,
                                              __half* __restrict__ h16) {
    __shared__ float W1s[32 * 64];
    __shared__ float W2s[64 * 64];
    __shared__ float b1s[64];
    __shared__ float b2s[64];
    for (int i = threadIdx.x; i < 32 * 64; i += 256) W1s[i] = W1[i];
    for (int i = threadIdx.x; i < 64 * 64; i += 256) W2s[i] = W2[i];
    if (threadIdx.x < 64) {
        b1s[threadIdx.x] = b1[threadIdx.x];
        b2s[threadIdx.x] = b2[threadIdx.x];
    }
    __syncthreads();

    int lane = threadIdx.x & 63;
    int cq = lane & 7;
    int g = lane >> 3;
    int gw = blockIdx.x * 4 + (threadIdx.x >> 6);
    int nwaves = gridDim.x * 4;

    for (int node = gw; node < NN; node += nwaves) {
        int s0 = P[node * NSP1];
        int s1 = P[node * NSP1 + NS];
        float4 sf = ((const float4*)x)[(size_t)node * 8 + cq];   // self: ch 4cq..4cq+3

        float ax0 = 0.f, ay0 = 0.f, az0 = 0.f, aw0 = 0.f;
        float ax1 = 0.f, ay1 = 0.f, az1 = 0.f, aw1 = 0.f;
        int e = s0;
        for (; e + 15 < s1; e += 16) {
            int c0 = col[e + g];
            int c1 = col[e + 8 + g];
            float2 f0 = x16f2[(size_t)c0 * 8 + cq];
            float2 f1 = x16f2[(size_t)c1 * 8 + cq];
            h4acc(f0, ax0, ay0, az0, aw0);
            h4acc(f1, ax1, ay1, az1, aw1);
        }
        for (int ee = e + g; ee < s1; ee += 8) {
            float2 f = x16f2[(size_t)col[ee] * 8 + cq];
            h4acc(f, ax0, ay0, az0, aw0);
        }
        float avx = ax0 + ax1, avy = ay0 + ay1, avz = az0 + az1, avw = aw0 + aw1;
        avx += __shfl_xor(avx, 8);  avy += __shfl_xor(avy, 8);
        avz += __shfl_xor(avz, 8);  avw += __shfl_xor(avw, 8);
        avx += __shfl_xor(avx, 16); avy += __shfl_xor(avy, 16);
        avz += __shfl_xor(avz, 16); avw += __shfl_xor(avw, 16);
        avx += __shfl_xor(avx, 32); avy += __shfl_xor(avy, 32);
        avz += __shfl_xor(avz, 32); avw += __shfl_xor(avw, 32);
        avx += sf.x; avy += sf.y; avz += sf.z; avw += sf.w;

        // MLP1: ch 4i+j -> rdlane(av[j], i), i = 0..7
        float sa = b1s[lane], sb = 0.f, sc = 0.f, sd = 0.f;
#pragma unroll
        for (int i = 0; i < 8; ++i) {
            sa = fmaf(rdlane(avx, i), W1s[(4 * i) * 64 + lane],     sa);
            sb = fmaf(rdlane(avy, i), W1s[(4 * i + 1) * 64 + lane], sb);
            sc = fmaf(rdlane(avz, i), W1s[(4 * i + 2) * 64 + lane], sc);
            sd = fmaf(rdlane(avw, i), W1s[(4 * i + 3) * 64 + lane], sd);
        }
        float t = fmaxf((sa + sb) + (sc + sd), 0.f);

        float s2a = b2s[lane], s2b = 0.f;
#pragma unroll
        for (int j = 0; j < 64; j += 2) {
            s2a = fmaf(rdlane(t, j),     W2s[j * 64 + lane],       s2a);
            s2b = fmaf(rdlane(t, j + 1), W2s[(j + 1) * 64 + lane], s2b);
        }
        h16[(size_t)node * 64 + lane] = __float2half(fmaxf(s2a + s2b, 0.f));
    }
}

// ============ layer 2: half4 gather(h16) + rdlane-MLP2 -> out ============
// lane = (edge slot g = lane>>4, 0..3) x (channel quad cq = lane&15 -> ch 4cq..4cq+3)
// 4 edges per VMEM instruction; 4-deep unroll (16 edges in flight per wave).
__global__ __launch_bounds__(256) void fused2(const float2* __restrict__ hf2,
                                              const int* __restrict__ P,
                                              const int* __restrict__ col,
                                              const float* __restrict__ W3,
                                              const float* __restrict__ b3,
                                              const float* __restrict__ W4,
                                              const float* __restrict__ b4,
                                              float* __restrict__ out) {
    __shared__ float W3s[64 * 64];
    __shared__ float W4s[64 * 32];
    __shared__ float b3s[64];
    __shared__ float b4s[32];
    for (int i = threadIdx.x; i < 64 * 64; i += 256) W3s[i] = W3[i];
    for (int i = threadIdx.x; i < 64 * 32; i += 256) W4s[i] = W4[i];
    if (threadIdx.x < 64) b3s[threadIdx.x] = b3[threadIdx.x];
    if (threadIdx.x < 32) b4s[threadIdx.x] = b4[threadIdx.x];
    __syncthreads();

    int lane = threadIdx.x & 63;
    int cq = lane & 15;
    int g = lane >> 4;
    int gw = blockIdx.x * 4 + (threadIdx.x >> 6);
    int nwaves = gridDim.x * 4;

    for (int node = gw; node < NN; node += nwaves) {
        int s0 = P[node * NSP1];
        int s1 = P[node * NSP1 + NS];
        float2 sfr = hf2[(size_t)node * 16 + cq];   // self: ch 4cq..4cq+3 (fp16)

        float ax0 = 0.f, ay0 = 0.f, az0 = 0.f, aw0 = 0.f;
        float ax1 = 0.f, ay1 = 0.f, az1 = 0.f, aw1 = 0.f;
        float ax2 = 0.f, ay2 = 0.f, az2 = 0.f, aw2 = 0.f;
        float ax3 = 0.f, ay3 = 0.f, az3 = 0.f, aw3 = 0.f;
        int e = s0;
        for (; e + 15 < s1; e += 16) {
            int c0 = col[e + g];
            int c1 = col[e + 4 + g];
            int c2 = col[e + 8 + g];
            int c3 = col[e + 12 + g];
            float2 f0 = hf2[(size_t)c0 * 16 + cq];
            float2 f1 = hf2[(size_t)c1 * 16 + cq];
            float2 f2 = hf2[(size_t)c2 * 16 + cq];
            float2 f3 = hf2[(size_t)c3 * 16 + cq];
            h4acc(f0, ax0, ay0, az0, aw0);
            h4acc(f1, ax1, ay1, az1, aw1);
            h4acc(f2, ax2, ay2, az2, aw2);
            h4acc(f3, ax3, ay3, az3, aw3);
        }
        for (int ee = e + g; ee < s1; ee += 4) {
            float2 f = hf2[(size_t)col[ee] * 16 + cq];
            h4acc(f, ax0, ay0, az0, aw0);
        }
        float avx = (ax0 + ax1) + (ax2 + ax3);
        float avy = (ay0 + ay1) + (ay2 + ay3);
        float avz = (az0 + az1) + (az2 + az3);
        float avw = (aw0 + aw1) + (aw2 + aw3);
        avx += __shfl_xor(avx, 16); avy += __shfl_xor(avy, 16);
        avz += __shfl_xor(avz, 16); avw += __shfl_xor(avw, 16);
        avx += __shfl_xor(avx, 32); avy += __shfl_xor(avy, 32);
        avz += __shfl_xor(avz, 32); avw += __shfl_xor(avw, 32);
        {
            __half2 lo = *reinterpret_cast<__half2*>(&sfr.x);
            __half2 hi = *reinterpret_cast<__half2*>(&sfr.y);
            float2 a = __half22float2(lo), b = __half22float2(hi);
            avx += a.x; avy += a.y; avz += b.x; avw += b.y;
        }

        // MLP2: ch 4i+j -> rdlane(av[j], i), i = 0..15
        float sa = b3s[lane], sb = 0.f, sc = 0.f, sd = 0.f;
#pragma unroll
        for (int i = 0; i < 16; ++i) {
            sa = fmaf(rdlane(avx, i), W3s[(4 * i) * 64 + lane],     sa);
            sb = fmaf(rdlane(avy, i), W3s[(4 * i + 1) * 64 + lane], sb);
            sc = fmaf(rdlane(avz, i), W3s[(4 * i + 2) * 64 + lane], sc);
            sd = fmaf(rdlane(avw, i), W3s[(4 * i + 3) * 64 + lane], sd);
        }
        float t = fmaxf((sa + sb) + (sc + sd), 0.f);

        float s2a = b4s[lane & 31], s2b = 0.f;
#pragma unroll
        for (int j = 0; j < 64; j += 2) {
            s2a = fmaf(rdlane(t, j),     W4s[j * 32 + (lane & 31)],       s2a);
            s2b = fmaf(rdlane(t, j + 1), W4s[(j + 1) * 32 + (lane & 31)], s2b);
        }
        if (lane < 32) out[(size_t)node * 32 + lane] = s2a + s2b;
    }
}

extern "C" void kernel_launch(void* const* d_in, const int* in_sizes, int n_in,
                              void* d_out, int out_size, void* d_ws, size_t ws_size,
                              hipStream_t stream) {
    const float* x  = (const float*)d_in[0];
    const int*   ei = (const int*)d_in[1];
    const float* W1 = (const float*)d_in[2];
    const float* b1 = (const float*)d_in[3];
    const float* W2 = (const float*)d_in[4];
    const float* b2 = (const float*)d_in[5];
    const float* W3 = (const float*)d_in[6];
    const float* b3 = (const float*)d_in[7];
    const float* W4 = (const float*)d_in[8];
    const float* b4 = (const float*)d_in[9];
    float* out = (float*)d_out;

    char* ws = (char*)d_ws;
    __half* h16 = (__half*)ws;                        ws += (size_t)NN * 64 * 2;       // 12.8 MB
    __half* x16 = (__half*)ws;                        ws += (size_t)NN * 32 * 2;       // 6.4 MB
    int*   col  = (int*)ws;                           ws += (size_t)NE * 4;            // 6.4 MB
    int*   P    = (int*)ws;                           ws += (size_t)NN * NSP1 * 4;     // 5.6 MB
    int*   deg2 = (int*)ws;                           ws += (size_t)NN * NS * 4;       // 5.2 MB
    int* scanned= (int*)ws;                           ws += (size_t)NN * 4;
    int*   bsums= (int*)ws;                           ws += (size_t)NB * 4;

    // ---- slice-bucketed CSR build + fp16 conversion ----
    hipMemsetAsync(deg2, 0, (size_t)NN * NS * 4, stream);
    cvt_k<<<(NN * 16 + 255) / 256, 256, 0, stream>>>((const float2*)x, (__half2*)x16);
    hist2_k<<<NE / 256, 256, 0, stream>>>(ei, deg2);
    scan1_k<<<NB, 256, 0, stream>>>(deg2, scanned, bsums);
    scan2_k<<<1, 512, 0, stream>>>(bsums);
    scan3b_k<<<NB, 256, 0, stream>>>(scanned, bsums, deg2, P);
    fill2_k<<<NE / 256, 256, 0, stream>>>(ei, P, col);

    // ---- fused layers ----
    fused1<<<1536, 256, 0, stream>>>(x, (const float2*)x16, P, col,
                                     W1, b1, W2, b2, h16);
    fused2<<<1536, 256, 0, stream>>>((const float2*)h16, P, col,
                                     W3, b3, W4, b4, out);
}

// Round 17
// 291.000 us; speedup vs baseline: 2.4163x; 1.4011x over previous
//
#include <hip/hip_runtime.h>
#include <hip/hip_fp16.h>

#define NN 100000
#define NE 1600000
#define NB 391        // ceil(NN/256)
#define NS 13         // src slices: slice = src >> 13
#define NSP1 14
#define SLICE_SHIFT 13
#define NSEG 391      // dst segments of 256 nodes: seg = dst >> 8
#define EPB 4096      // edges per fillA/seghist block
#define GRID_E 391    // ceil(NE/EPB)

__device__ __forceinline__ float rdlane(float v, int i) {
    return __uint_as_float(__builtin_amdgcn_readlane(__float_as_uint(v), (unsigned)i));
}

__device__ __forceinline__ void h4acc(float2 raw, float& ax, float& ay, float& az, float& aw) {
    __half2 lo = *reinterpret_cast<__half2*>(&raw.x);
    __half2 hi = *reinterpret_cast<__half2*>(&raw.y);
    float2 a = __half22float2(lo);
    float2 b = __half22float2(hi);
    ax += a.x; ay += a.y; az += b.x; aw += b.y;
}

// ===================== build phase A: segment sort =====================

// segment sizes (LDS-staged histogram)
__global__ __launch_bounds__(256) void seghist_k(const int* __restrict__ ei,
                                                 int* __restrict__ segcnt) {
    __shared__ int cnt[NSEG];
    for (int i = threadIdx.x; i < NSEG; i += 256) cnt[i] = 0;
    __syncthreads();
    int eb = blockIdx.x * EPB;
    int ee = (eb + EPB < NE) ? eb + EPB : NE;
    for (int e = eb + threadIdx.x; e < ee; e += 256)
        atomicAdd(&cnt[ei[NE + e] >> 8], 1);
    __syncthreads();
    for (int i = threadIdx.x; i < NSEG; i += 256)
        if (cnt[i]) atomicAdd(&segcnt[i], cnt[i]);
}

// exclusive starts of segments + cursor copy (1 block)
__global__ __launch_bounds__(512) void segscan_k(const int* __restrict__ segcnt,
                                                 int* __restrict__ segstart,
                                                 int* __restrict__ cursorA) {
    __shared__ int tmp[512];
    int t = threadIdx.x;
    int v = (t < NSEG) ? segcnt[t] : 0;
    tmp[t] = v;
    __syncthreads();
#pragma unroll
    for (int off = 1; off < 512; off <<= 1) {
        int u = (t >= off) ? tmp[t - off] : 0;
        __syncthreads();
        tmp[t] += u;
        __syncthreads();
    }
    if (t < NSEG) {
        int excl = tmp[t] - v;
        segstart[t] = excl;
        cursorA[t] = excl;
    }
    if (t == 0) segstart[NSEG] = NE;
}

// bin edges into segments via LDS staging; packed payload (dst&255)<<17 | src
__global__ __launch_bounds__(256) void fillA_k(const int* __restrict__ ei,
                                               int* __restrict__ cursorA,
                                               int* __restrict__ segbuf) {
    __shared__ int cnt[NSEG];
    __shared__ int base[NSEG];
    for (int i = threadIdx.x; i < NSEG; i += 256) cnt[i] = 0;
    __syncthreads();

    int eb = blockIdx.x * EPB;
    int pay[16], sb[16];
#pragma unroll
    for (int k = 0; k < 16; ++k) {
        int e = eb + k * 256 + threadIdx.x;
        sb[k] = -1;
        pay[k] = 0;
        if (e < NE) {
            int src = ei[e];
            int dst = ei[NE + e];
            int seg = dst >> 8;
            int off = atomicAdd(&cnt[seg], 1);
            pay[k] = ((dst & 255) << 17) | src;
            sb[k] = (seg << 12) | off;
        }
    }
    __syncthreads();
    for (int b = threadIdx.x; b < NSEG; b += 256)
        base[b] = cnt[b] ? atomicAdd(&cursorA[b], cnt[b]) : 0;
    __syncthreads();
#pragma unroll
    for (int k = 0; k < 16; ++k) {
        if (sb[k] >= 0) {
            int seg = sb[k] >> 12;
            int off = sb[k] & 4095;
            segbuf[base[seg] + off] = pay[k];
        }
    }
}

// ===================== build phase B: per-segment deg2 + final scatter =====================

// block = segment: LDS histogram over 256x13 buckets, coalesced deg2 overwrite
__global__ __launch_bounds__(256) void deghist_k(const int* __restrict__ segbuf,
                                                 const int* __restrict__ segstart,
                                                 int* __restrict__ deg2) {
    __shared__ int cnt[256 * NS];
    for (int i = threadIdx.x; i < 256 * NS; i += 256) cnt[i] = 0;
    __syncthreads();
    int s0 = segstart[blockIdx.x], s1 = segstart[blockIdx.x + 1];
    for (int e = s0 + threadIdx.x; e < s1; e += 256) {
        int pk = segbuf[e];
        int l = pk >> 17;
        int src = pk & 0x1FFFF;
        atomicAdd(&cnt[l * NS + (src >> SLICE_SHIFT)], 1);
    }
    __syncthreads();
    int n = blockIdx.x * 256 + threadIdx.x;
    if (n < NN) {
#pragma unroll
        for (int s = 0; s < NS; ++s)
            deg2[n * NS + s] = cnt[threadIdx.x * NS + s];
    }
}

__global__ __launch_bounds__(256) void scan1_k(const int* __restrict__ deg2,
                                               int* __restrict__ scanned,
                                               int* __restrict__ bsums) {
    __shared__ int tmp[256];
    int i = blockIdx.x * 256 + threadIdx.x;
    int v = 0;
    if (i < NN) {
#pragma unroll
        for (int k = 0; k < NS; ++k) v += deg2[i * NS + k];
    }
    tmp[threadIdx.x] = v;
    __syncthreads();
#pragma unroll
    for (int off = 1; off < 256; off <<= 1) {
        int t = (threadIdx.x >= off) ? tmp[threadIdx.x - off] : 0;
        __syncthreads();
        tmp[threadIdx.x] += t;
        __syncthreads();
    }
    if (i < NN) scanned[i] = tmp[threadIdx.x];
    if (threadIdx.x == 255) bsums[blockIdx.x] = tmp[255];
}

__global__ __launch_bounds__(512) void scan2_k(int* __restrict__ bsums) {
    __shared__ int tmp[512];
    int v = (threadIdx.x < NB) ? bsums[threadIdx.x] : 0;
    tmp[threadIdx.x] = v;
    __syncthreads();
#pragma unroll
    for (int off = 1; off < 512; off <<= 1) {
        int t = (threadIdx.x >= off) ? tmp[threadIdx.x - off] : 0;
        __syncthreads();
        tmp[threadIdx.x] += t;
        __syncthreads();
    }
    if (threadIdx.x < NB) bsums[threadIdx.x] = tmp[threadIdx.x];
}

// P[n][0] = row start; P[n][s+1] = start of bucket s (NOT mutated later).
// Row end of n = P[(n+1)][0]; sentinel P[NN][0] = NE.
__global__ __launch_bounds__(256) void scan3b_k(const int* __restrict__ scanned,
                                                const int* __restrict__ bsums,
                                                const int* __restrict__ deg2,
                                                int* __restrict__ P) {
    int i = blockIdx.x * 256 + threadIdx.x;
    if (i < NN) {
        int d = 0;
#pragma unroll
        for (int k = 0; k < NS; ++k) d += deg2[i * NS + k];
        int incl = scanned[i] + (blockIdx.x ? bsums[blockIdx.x - 1] : 0);
        int run = incl - d;
        P[i * NSP1 + 0] = run;
#pragma unroll
        for (int s = 0; s < NS; ++s) {
            P[i * NSP1 + s + 1] = run;
            run += deg2[i * NS + s];
        }
        if (i == NN - 1) P[NN * NSP1] = incl;   // sentinel = NE
    }
}

// block = segment: scatter col within segment's private range, cursors in LDS
__global__ __launch_bounds__(256) void fillB_k(const int* __restrict__ segbuf,
                                               const int* __restrict__ segstart,
                                               const int* __restrict__ P,
                                               int* __restrict__ col) {
    __shared__ int cur[256 * NS];
    int n = blockIdx.x * 256 + threadIdx.x;
    if (n < NN) {
#pragma unroll
        for (int s = 0; s < NS; ++s)
            cur[threadIdx.x * NS + s] = P[n * NSP1 + s + 1];
    }
    __syncthreads();
    int s0 = segstart[blockIdx.x], s1 = segstart[blockIdx.x + 1];
    for (int e = s0 + threadIdx.x; e < s1; e += 256) {
        int pk = segbuf[e];
        int l = pk >> 17;
        int src = pk & 0x1FFFF;
        int pos = atomicAdd(&cur[l * NS + (src >> SLICE_SHIFT)], 1);
        col[pos] = src;
    }
}

// ---- x (f32) -> x16 (half-packed) ----
__global__ __launch_bounds__(256) void cvt_k(const float2* __restrict__ x2,
                                             __half2* __restrict__ x16) {
    int i = blockIdx.x * 256 + threadIdx.x;
    if (i < NN * 16) {
        float2 v = x2[i];
        x16[i] = __floats2half2_rn(v.x, v.y);
    }
}

// ============ layer 1: half4 gather(x16) + rdlane-MLP1 -> h16 (frozen, end idx changed) ============
__global__ __launch_bounds__(256) void fused1(const float* __restrict__ x,
                                              const float2* __restrict__ x16f2,
                                              const int* __restrict__ P,
                                              const int* __restrict__ col,
                                              const float* __restrict__ W1,
                                              const float* __restrict__ b1,
                                              const float* __restrict__ W2,
                                              const float* __restrict__ b2,
                                              __half* __restrict__ h16) {
    __shared__ float W1s[32 * 64];
    __shared__ float W2s[64 * 64];
    __shared__ float b1s[64];
    __shared__ float b2s[64];
    for (int i = threadIdx.x; i < 32 * 64; i += 256) W1s[i] = W1[i];
    for (int i = threadIdx.x; i < 64 * 64; i += 256) W2s[i] = W2[i];
    if (threadIdx.x < 64) {
        b1s[threadIdx.x] = b1[threadIdx.x];
        b2s[threadIdx.x] = b2[threadIdx.x];
    }
    __syncthreads();

    int lane = threadIdx.x & 63;
    int cq = lane & 7;
    int g = lane >> 3;
    int gw = blockIdx.x * 4 + (threadIdx.x >> 6);
    int nwaves = gridDim.x * 4;

    for (int node = gw; node < NN; node += nwaves) {
        int s0 = P[node * NSP1];
        int s1 = P[(node + 1) * NSP1];
        float4 sf = ((const float4*)x)[(size_t)node * 8 + cq];

        float ax0 = 0.f, ay0 = 0.f, az0 = 0.f, aw0 = 0.f;
        float ax1 = 0.f, ay1 = 0.f, az1 = 0.f, aw1 = 0.f;
        int e = s0;
        for (; e + 15 < s1; e += 16) {
            int c0 = col[e + g];
            int c1 = col[e + 8 + g];
            float2 f0 = x16f2[(size_t)c0 * 8 + cq];
            float2 f1 = x16f2[(size_t)c1 * 8 + cq];
            h4acc(f0, ax0, ay0, az0, aw0);
            h4acc(f1, ax1, ay1, az1, aw1);
        }
        for (int ee = e + g; ee < s1; ee += 8) {
            float2 f = x16f2[(size_t)col[ee] * 8 + cq];
            h4acc(f, ax0, ay0, az0, aw0);
        }
        float avx = ax0 + ax1, avy = ay0 + ay1, avz = az0 + az1, avw = aw0 + aw1;
        avx += __shfl_xor(avx, 8);  avy += __shfl_xor(avy, 8);
        avz += __shfl_xor(avz, 8);  avw += __shfl_xor(avw, 8);
        avx += __shfl_xor(avx, 16); avy += __shfl_xor(avy, 16);
        avz += __shfl_xor(avz, 16); avw += __shfl_xor(avw, 16);
        avx += __shfl_xor(avx, 32); avy += __shfl_xor(avy, 32);
        avz += __shfl_xor(avz, 32); avw += __shfl_xor(avw, 32);
        avx += sf.x; avy += sf.y; avz += sf.z; avw += sf.w;

        float sa = b1s[lane], sb = 0.f, sc = 0.f, sd = 0.f;
#pragma unroll
        for (int i = 0; i < 8; ++i) {
            sa = fmaf(rdlane(avx, i), W1s[(4 * i) * 64 + lane],     sa);
            sb = fmaf(rdlane(avy, i), W1s[(4 * i + 1) * 64 + lane], sb);
            sc = fmaf(rdlane(avz, i), W1s[(4 * i + 2) * 64 + lane], sc);
            sd = fmaf(rdlane(avw, i), W1s[(4 * i + 3) * 64 + lane], sd);
        }
        float t = fmaxf((sa + sb) + (sc + sd), 0.f);

        float s2a = b2s[lane], s2b = 0.f;
#pragma unroll
        for (int j = 0; j < 64; j += 2) {
            s2a = fmaf(rdlane(t, j),     W2s[j * 64 + lane],       s2a);
            s2b = fmaf(rdlane(t, j + 1), W2s[(j + 1) * 64 + lane], s2b);
        }
        h16[(size_t)node * 64 + lane] = __float2half(fmaxf(s2a + s2b, 0.f));
    }
}

// ============ layer 2: half4 gather(h16) + rdlane-MLP2 -> out (frozen, end idx changed) ============
__global__ __launch_bounds__(256) void fused2(const float2* __restrict__ hf2,
                                              const int* __restrict__ P,
                                              const int* __restrict__ col,
                                              const float* __restrict__ W3,
                                              const float* __restrict__ b3,
                                              const float* __restrict__ W4,
                                              const float* __restrict__ b4,
                                              float* __restrict__ out) {
    __shared__ float W3s[64 * 64];
    __shared__ float W4s[64 * 32];
    __shared__ float b3s[64];
    __shared__ float b4s[32];
    for (int i = threadIdx.x; i < 64 * 64; i += 256) W3s[i] = W3[i];
    for (int i = threadIdx.x; i < 64 * 32; i += 256) W4s[i] = W4[i];
    if (threadIdx.x < 64) b3s[threadIdx.x] = b3[threadIdx.x];
    if (threadIdx.x < 32) b4s[threadIdx.x] = b4[threadIdx.x];
    __syncthreads();

    int lane = threadIdx.x & 63;
    int cq = lane & 15;
    int g = lane >> 4;
    int gw = blockIdx.x * 4 + (threadIdx.x >> 6);
    int nwaves = gridDim.x * 4;

    for (int node = gw; node < NN; node += nwaves) {
        int s0 = P[node * NSP1];
        int s1 = P[(node + 1) * NSP1];
        float2 sfr = hf2[(size_t)node * 16 + cq];

        float ax0 = 0.f, ay0 = 0.f, az0 = 0.f, aw0 = 0.f;
        float ax1 = 0.f, ay1 = 0.f, az1 = 0.f, aw1 = 0.f;
        float ax2 = 0.f, ay2 = 0.f, az2 = 0.f, aw2 = 0.f;
        float ax3 = 0.f, ay3 = 0.f, az3 = 0.f, aw3 = 0.f;
        int e = s0;
        for (; e + 15 < s1; e += 16) {
            int c0 = col[e + g];
            int c1 = col[e + 4 + g];
            int c2 = col[e + 8 + g];
            int c3 = col[e + 12 + g];
            float2 f0 = hf2[(size_t)c0 * 16 + cq];
            float2 f1 = hf2[(size_t)c1 * 16 + cq];
            float2 f2 = hf2[(size_t)c2 * 16 + cq];
            float2 f3 = hf2[(size_t)c3 * 16 + cq];
            h4acc(f0, ax0, ay0, az0, aw0);
            h4acc(f1, ax1, ay1, az1, aw1);
            h4acc(f2, ax2, ay2, az2, aw2);
            h4acc(f3, ax3, ay3, az3, aw3);
        }
        for (int ee = e + g; ee < s1; ee += 4) {
            float2 f = hf2[(size_t)col[ee] * 16 + cq];
            h4acc(f, ax0, ay0, az0, aw0);
        }
        float avx = (ax0 + ax1) + (ax2 + ax3);
        float avy = (ay0 + ay1) + (ay2 + ay3);
        float avz = (az0 + az1) + (az2 + az3);
        float avw = (aw0 + aw1) + (aw2 + aw3);
        avx += __shfl_xor(avx, 16); avy += __shfl_xor(avy, 16);
        avz += __shfl_xor(avz, 16); avw += __shfl_xor(avw, 16);
        avx += __shfl_xor(avx, 32); avy += __shfl_xor(avy, 32);
        avz += __shfl_xor(avz, 32); avw += __shfl_xor(avw, 32);
        {
            __half2 lo = *reinterpret_cast<__half2*>(&sfr.x);
            __half2 hi = *reinterpret_cast<__half2*>(&sfr.y);
            float2 a = __half22float2(lo), b = __half22float2(hi);
            avx += a.x; avy += a.y; avz += b.x; avw += b.y;
        }

        float sa = b3s[lane], sb = 0.f, sc = 0.f, sd = 0.f;
#pragma unroll
        for (int i = 0; i < 16; ++i) {
            sa = fmaf(rdlane(avx, i), W3s[(4 * i) * 64 + lane],     sa);
            sb = fmaf(rdlane(avy, i), W3s[(4 * i + 1) * 64 + lane], sb);
            sc = fmaf(rdlane(avz, i), W3s[(4 * i + 2) * 64 + lane], sc);
            sd = fmaf(rdlane(avw, i), W3s[(4 * i + 3) * 64 + lane], sd);
        }
        float t = fmaxf((sa + sb) + (sc + sd), 0.f);

        float s2a = b4s[lane & 31], s2b = 0.f;
#pragma unroll
        for (int j = 0; j < 64; j += 2) {
            s2a = fmaf(rdlane(t, j),     W4s[j * 32 + (lane & 31)],       s2a);
            s2b = fmaf(rdlane(t, j + 1), W4s[(j + 1) * 32 + (lane & 31)], s2b);
        }
        if (lane < 32) out[(size_t)node * 32 + lane] = s2a + s2b;
    }
}

extern "C" void kernel_launch(void* const* d_in, const int* in_sizes, int n_in,
                              void* d_out, int out_size, void* d_ws, size_t ws_size,
                              hipStream_t stream) {
    const float* x  = (const float*)d_in[0];
    const int*   ei = (const int*)d_in[1];
    const float* W1 = (const float*)d_in[2];
    const float* b1 = (const float*)d_in[3];
    const float* W2 = (const float*)d_in[4];
    const float* b2 = (const float*)d_in[5];
    const float* W3 = (const float*)d_in[6];
    const float* b3 = (const float*)d_in[7];
    const float* W4 = (const float*)d_in[8];
    const float* b4 = (const float*)d_in[9];
    float* out = (float*)d_out;

    char* ws = (char*)d_ws;
    __half* h16   = (__half*)ws;                      ws += (size_t)NN * 64 * 2;           // 12.8 MB
    __half* x16   = (__half*)ws;                      ws += (size_t)NN * 32 * 2;           // 6.4 MB
    int*   col    = (int*)ws;                         ws += (size_t)NE * 4;                // 6.4 MB
    int*   P      = (int*)ws;                         ws += (size_t)(NN * NSP1 + 1) * 4;   // 5.6 MB
    int*   deg2   = (int*)ws;                         ws += (size_t)NN * NS * 4;           // 5.2 MB
    int*   segbuf = (int*)ws;                         ws += (size_t)NE * 4;                // 6.4 MB
    int* scanned  = (int*)ws;                         ws += (size_t)NN * 4;
    int*   bsums  = (int*)ws;                         ws += (size_t)NB * 4;
    int*  segcnt  = (int*)ws;                         ws += (size_t)NSEG * 4;
    int* segstart = (int*)ws;                         ws += (size_t)(NSEG + 1) * 4;
    int* cursorA  = (int*)ws;                         ws += (size_t)NSEG * 4;

    // ---- build: two-phase LDS-staged radix ----
    hipMemsetAsync(segcnt, 0, (size_t)NSEG * 4, stream);
    cvt_k<<<(NN * 16 + 255) / 256, 256, 0, stream>>>((const float2*)x, (__half2*)x16);
    seghist_k<<<GRID_E, 256, 0, stream>>>(ei, segcnt);
    segscan_k<<<1, 512, 0, stream>>>(segcnt, segstart, cursorA);
    fillA_k<<<GRID_E, 256, 0, stream>>>(ei, cursorA, segbuf);
    deghist_k<<<NSEG, 256, 0, stream>>>(segbuf, segstart, deg2);
    scan1_k<<<NB, 256, 0, stream>>>(deg2, scanned, bsums);
    scan2_k<<<1, 512, 0, stream>>>(bsums);
    scan3b_k<<<NB, 256, 0, stream>>>(scanned, bsums, deg2, P);
    fillB_k<<<NSEG, 256, 0, stream>>>(segbuf, segstart, P, col);

    // ---- fused layers (frozen) ----
    fused1<<<1536, 256, 0, stream>>>(x, (const float2*)x16, P, col,
                                     W1, b1, W2, b2, h16);
    fused2<<<1536, 256, 0, stream>>>((const float2*)h16, P, col,
                                     W3, b3, W4, b4, out);
}